// Round 6
// baseline (439.527 us; speedup 1.0000x reference)
//
#include <hip/hip_runtime.h>

#define N_NODES 50000
#define E_EDGES 600000
#define LLM_DIM 640
#define HIDDEN 128
#define POUT 112
#define NB_SCAN 98   // ceil(50000/512)

typedef __attribute__((ext_vector_type(8))) short bf16x8;
typedef __attribute__((ext_vector_type(4))) float f32x4;

__device__ inline unsigned short f2bf(float f) {
    unsigned u = __float_as_uint(f);
    u += 0x7fff + ((u >> 16) & 1);   // RNE
    return (unsigned short)(u >> 16);
}
__device__ inline float bflo(unsigned v) { return __uint_as_float(v << 16); }
__device__ inline float bfhi(unsigned v) { return __uint_as_float(v & 0xffff0000u); }

__device__ inline bf16x8 packbf(float4 lo, float4 hi) {
    bf16x8 r;
    r[0] = (short)f2bf(lo.x); r[1] = (short)f2bf(lo.y);
    r[2] = (short)f2bf(lo.z); r[3] = (short)f2bf(lo.w);
    r[4] = (short)f2bf(hi.x); r[5] = (short)f2bf(hi.y);
    r[6] = (short)f2bf(hi.z); r[7] = (short)f2bf(hi.w);
    return r;
}

// ---------------- degree count (int) ----------------
__global__ void deg_count(const int* __restrict__ eidx, int* __restrict__ cnt) {
    int e = blockIdx.x * 256 + threadIdx.x;
    if (e < E_EDGES) atomicAdd(&cnt[eidx[E_EDGES + e]], 1);
}

__global__ void make_dis(const int* __restrict__ cnt, float* __restrict__ dis) {
    int i = blockIdx.x * 256 + threadIdx.x;
    if (i < N_NODES) dis[i] = rsqrtf(1.0f + (float)cnt[i]);
}

// ---------------- 3-kernel exclusive scan over cnt -> offs ----------------
__global__ __launch_bounds__(256) void scan_blocksum(const int* __restrict__ cnt, int* __restrict__ bsum) {
    __shared__ int s[256];
    int b = blockIdx.x, t = threadIdx.x;
    int i0 = b * 512 + t, i1 = i0 + 256;
    int v = (i0 < N_NODES ? cnt[i0] : 0) + (i1 < N_NODES ? cnt[i1] : 0);
    s[t] = v;
    __syncthreads();
    for (int st = 128; st; st >>= 1) {
        if (t < st) s[t] += s[t + st];
        __syncthreads();
    }
    if (t == 0) bsum[b] = s[0];
}

__global__ void scan_bsum(const int* __restrict__ bsum, int* __restrict__ bpre) {
    __shared__ int s[128];
    int t = threadIdx.x;
    if (t < NB_SCAN) s[t] = bsum[t];
    __syncthreads();
    if (t == 0) {
        int a = 0;
        for (int i = 0; i < NB_SCAN; i++) { int v = s[i]; s[i] = a; a += v; }
    }
    __syncthreads();
    if (t < NB_SCAN) bpre[t] = s[t];
}

__global__ __launch_bounds__(256) void scan_offs(const int* __restrict__ cnt, const int* __restrict__ bpre,
                                                 int* __restrict__ offs) {
    __shared__ int sA[512], sB[512];
    int b = blockIdx.x, t = threadIdx.x;
    int i0 = b * 512 + t, i1 = i0 + 256;
    int v0 = (i0 < N_NODES ? cnt[i0] : 0);
    int v1 = (i1 < N_NODES ? cnt[i1] : 0);
    sA[t] = v0; sA[t + 256] = v1;
    int* src = sA; int* dst = sB;
    for (int st = 1; st < 512; st <<= 1) {
        __syncthreads();
        dst[t]       = src[t]       + (t       >= st ? src[t - st]       : 0);
        dst[t + 256] = src[t + 256] + (t + 256 >= st ? src[t + 256 - st] : 0);
        int* tmp = src; src = dst; dst = tmp;
    }
    __syncthreads();
    int base = bpre[b];
    if (i0 < N_NODES) offs[i0] = base + src[t] - v0;
    if (i1 < N_NODES) offs[i1] = base + src[t + 256] - v1;
    if (b == 0 && t == 0) offs[N_NODES] = E_EDGES;
}

__global__ void fill_srcs(const int* __restrict__ eidx, const int* __restrict__ offs,
                          int* __restrict__ pos, int* __restrict__ srcs) {
    int e = blockIdx.x * 256 + threadIdx.x;
    if (e >= E_EDGES) return;
    int s = eidx[e];
    int d = eidx[E_EDGES + e];
    int p = atomicAdd(&pos[d], 1);
    srcs[offs[d] + p] = s;
}

// ---------------- weight converts ----------------
__global__ void wt_convert(const float* __restrict__ W, unsigned short* __restrict__ Wt) {
    int idx = blockIdx.x * 256 + threadIdx.x;
    if (idx >= POUT * LLM_DIM) return;
    int n = idx / LLM_DIM;
    int k = idx - n * LLM_DIM;
    Wt[(size_t)n * LLM_DIM + k] = f2bf(W[(size_t)k * POUT + n]);
}

__global__ void w2_convert(const float* __restrict__ W, unsigned short* __restrict__ Wt2) {
    int idx = blockIdx.x * 256 + threadIdx.x;
    if (idx >= 2 * HIDDEN * HIDDEN) return;
    int l = idx >> 14;
    int rem = idx & 16383;
    int n = rem >> 7;
    int k = rem & 127;
    Wt2[idx] = f2bf(W[l * 16384 + k * 128 + n]);
}

// ---------------- projection: LDS-free direct-fragment MFMA ----------------
// One wave per 16 rows (50000 = 16*3125 exactly). A frags from global fp32
// (convert in reg), B frags from L2-resident Wt[n][k]. No barriers; depth-3
// software pipeline over 20 K-chunks keeps ~27 loads in flight per wave.
__global__ __launch_bounds__(256) void proj_mfma(const float* __restrict__ A,
                                                 const unsigned short* __restrict__ Wt,
                                                 const float* __restrict__ bias,
                                                 const float* __restrict__ emb,
                                                 const int* __restrict__ sid,
                                                 const float* __restrict__ dis,
                                                 float* __restrict__ X,
                                                 unsigned short* __restrict__ Xs) {
    const int lane = threadIdx.x & 63;
    const int gw = (blockIdx.x * 256 + threadIdx.x) >> 6;
    const int row0 = gw * 16;
    if (row0 >= N_NODES) return;
    const int l15 = lane & 15, l4 = lane >> 4;

    const float* ap = A + (size_t)(row0 + l15) * LLM_DIM + l4 * 8;
    const unsigned short* bp = Wt + (size_t)l15 * LLM_DIM + l4 * 8;

    f32x4 acc[7];
#pragma unroll
    for (int j = 0; j < 7; j++) acc[j] = (f32x4){0.f, 0.f, 0.f, 0.f};

    float4 al[3], ah[3];
    bf16x8 bb[3][7];
    auto loadc = [&](int s, int k0) {
        al[s] = *reinterpret_cast<const float4*>(ap + k0);
        ah[s] = *reinterpret_cast<const float4*>(ap + k0 + 4);
#pragma unroll
        for (int ct = 0; ct < 7; ct++)
            bb[s][ct] = *reinterpret_cast<const bf16x8*>(bp + (size_t)ct * 16 * LLM_DIM + k0);
    };

    loadc(0, 0);
    loadc(1, 32);
#pragma unroll
    for (int i = 0; i < 20; i++) {
        const int s = i % 3;
        if (i + 2 < 20) loadc((i + 2) % 3, (i + 2) * 32);
        bf16x8 af = packbf(al[s], ah[s]);
#pragma unroll
        for (int ct = 0; ct < 7; ct++)
            acc[ct] = __builtin_amdgcn_mfma_f32_16x16x32_bf16(af, bb[s][ct], acc[ct], 0, 0, 0);
    }

    // epilogue: C/D layout col=lane&15, row=(lane>>4)*4+reg (validated)
#pragma unroll
    for (int r = 0; r < 4; r++) {
        int row = row0 + l4 * 4 + r;
        float d = dis[row];
#pragma unroll
        for (int ct = 0; ct < 7; ct++) {
            int col = ct * 16 + l15;
            float v = acc[ct][r] + bias[col];
            X[(size_t)row * HIDDEN + col] = v;
            Xs[(size_t)row * HIDDEN + col] = f2bf(d * v);
        }
        float e = emb[sid[row] * 16 + l15];
        X[(size_t)row * HIDDEN + POUT + l15] = e;
        Xs[(size_t)row * HIDDEN + POUT + l15] = f2bf(d * e);
    }
}

// ---------------- CSR gather on bf16: Gb[i] = bf16(dis_i*(sum Xs[src] + Xs[i])) ----------------
__global__ __launch_bounds__(256) void gather(const unsigned short* __restrict__ Xs,
                                              const int* __restrict__ offs,
                                              const int* __restrict__ srcs,
                                              const float* __restrict__ dis,
                                              unsigned short* __restrict__ Gb) {
    int node = blockIdx.x * 4 + (threadIdx.x >> 6);
    int lane = threadIdx.x & 63;
    if (node >= N_NODES) return;
    int beg = __builtin_amdgcn_readfirstlane(offs[node]);
    int end = __builtin_amdgcn_readfirstlane(offs[node + 1]);
    const unsigned* X32 = reinterpret_cast<const unsigned*>(Xs);
    float ax = 0.f, ay = 0.f;
    int e = beg;
    while (e < end) {
        int n = end - e;
        if (n > 64) n = 64;
        int idx = (lane < n) ? srcs[e + lane] : 0;
        int j = 0;
        for (; j + 8 <= n; j += 8) {
            int s0 = __shfl(idx, j);
            int s1 = __shfl(idx, j + 1);
            int s2 = __shfl(idx, j + 2);
            int s3 = __shfl(idx, j + 3);
            int s4 = __shfl(idx, j + 4);
            int s5 = __shfl(idx, j + 5);
            int s6 = __shfl(idx, j + 6);
            int s7 = __shfl(idx, j + 7);
            unsigned v0 = X32[(size_t)s0 * 64 + lane];
            unsigned v1 = X32[(size_t)s1 * 64 + lane];
            unsigned v2 = X32[(size_t)s2 * 64 + lane];
            unsigned v3 = X32[(size_t)s3 * 64 + lane];
            unsigned v4 = X32[(size_t)s4 * 64 + lane];
            unsigned v5 = X32[(size_t)s5 * 64 + lane];
            unsigned v6 = X32[(size_t)s6 * 64 + lane];
            unsigned v7 = X32[(size_t)s7 * 64 + lane];
            ax += ((bflo(v0) + bflo(v1)) + (bflo(v2) + bflo(v3))) +
                  ((bflo(v4) + bflo(v5)) + (bflo(v6) + bflo(v7)));
            ay += ((bfhi(v0) + bfhi(v1)) + (bfhi(v2) + bfhi(v3))) +
                  ((bfhi(v4) + bfhi(v5)) + (bfhi(v6) + bfhi(v7)));
        }
        for (; j < n; j++) {
            int s = __shfl(idx, j);
            unsigned v = X32[(size_t)s * 64 + lane];
            ax += bflo(v);
            ay += bfhi(v);
        }
        e += 64;
    }
    float d = dis[node];
    unsigned sv = X32[(size_t)node * 64 + lane];
    ax = d * (ax + bflo(sv));   // self term = dis_i * Xs_i
    ay = d * (ay + bfhi(sv));
    reinterpret_cast<unsigned*>(Gb)[(size_t)node * 64 + lane] =
        (unsigned)f2bf(ax) | ((unsigned)f2bf(ay) << 16);
}

// ---------------- fused GEMM + residual + relu (+Xs emit / +LayerNorm), LDS-free ----------------
// MODE 0: X += relu(Gb@W + b); Xs2 = bf16(dis*X)
// MODE 1: X = LayerNorm(X + relu(Gb@W + b))
template <int MODE>
__global__ __launch_bounds__(256) void gemm_fin(const unsigned short* __restrict__ Gb,
                                                const unsigned short* __restrict__ Wt2,
                                                const float* __restrict__ bias,
                                                const float* __restrict__ dis,
                                                const float* __restrict__ lng,
                                                const float* __restrict__ lnb,
                                                float* __restrict__ X,
                                                unsigned short* __restrict__ Xs2) {
    const int lane = threadIdx.x & 63;
    const int gw = (blockIdx.x * 256 + threadIdx.x) >> 6;
    const int row0 = gw * 16;
    if (row0 >= N_NODES) return;
    const int l15 = lane & 15, l4 = lane >> 4;

    const unsigned short* ap = Gb + (size_t)(row0 + l15) * HIDDEN + l4 * 8;
    const unsigned short* bp = Wt2 + (size_t)l15 * HIDDEN + l4 * 8;

    f32x4 acc[8];
#pragma unroll
    for (int j = 0; j < 8; j++) acc[j] = (f32x4){0.f, 0.f, 0.f, 0.f};

    bf16x8 aa[2];
    bf16x8 bb[2][8];
    auto loadc = [&](int s, int k0) {
        aa[s] = *reinterpret_cast<const bf16x8*>(ap + k0);
#pragma unroll
        for (int ct = 0; ct < 8; ct++)
            bb[s][ct] = *reinterpret_cast<const bf16x8*>(bp + (size_t)ct * 16 * HIDDEN + k0);
    };

    loadc(0, 0);
#pragma unroll
    for (int i = 0; i < 4; i++) {
        const int s = i & 1;
        if (i + 1 < 4) loadc(s ^ 1, (i + 1) * 32);
#pragma unroll
        for (int ct = 0; ct < 8; ct++)
            acc[ct] = __builtin_amdgcn_mfma_f32_16x16x32_bf16(aa[s], bb[s][ct], acc[ct], 0, 0, 0);
    }

    // epilogue
    float bcol[8];
#pragma unroll
    for (int ct = 0; ct < 8; ct++) bcol[ct] = bias[ct * 16 + l15];

    float vv[8][4];
#pragma unroll
    for (int r = 0; r < 4; r++) {
        int row = row0 + l4 * 4 + r;
#pragma unroll
        for (int ct = 0; ct < 8; ct++) {
            float xo = X[(size_t)row * HIDDEN + ct * 16 + l15];
            vv[ct][r] = xo + fmaxf(acc[ct][r] + bcol[ct], 0.f);
        }
    }

    if (MODE == 0) {
#pragma unroll
        for (int r = 0; r < 4; r++) {
            int row = row0 + l4 * 4 + r;
            float d = dis[row];
#pragma unroll
            for (int ct = 0; ct < 8; ct++) {
                int col = ct * 16 + l15;
                X[(size_t)row * HIDDEN + col] = vv[ct][r];
                Xs2[(size_t)row * HIDDEN + col] = f2bf(d * vv[ct][r]);
            }
        }
    } else {
        float s[4], q2[4];
#pragma unroll
        for (int r = 0; r < 4; r++) {
            s[r] = 0.f; q2[r] = 0.f;
#pragma unroll
            for (int ct = 0; ct < 8; ct++) {
                s[r] += vv[ct][r];
                q2[r] += vv[ct][r] * vv[ct][r];
            }
        }
#pragma unroll
        for (int off = 1; off < 16; off <<= 1) {
#pragma unroll
            for (int r = 0; r < 4; r++) {
                s[r] += __shfl_xor(s[r], off);
                q2[r] += __shfl_xor(q2[r], off);
            }
        }
        float gcol[8], bcol2[8];
#pragma unroll
        for (int ct = 0; ct < 8; ct++) {
            gcol[ct] = lng[ct * 16 + l15];
            bcol2[ct] = lnb[ct * 16 + l15];
        }
#pragma unroll
        for (int r = 0; r < 4; r++) {
            int row = row0 + l4 * 4 + r;
            float mean = s[r] * (1.f / 128.f);
            float var = q2[r] * (1.f / 128.f) - mean * mean;
            float inv = rsqrtf(var + 1e-5f);
#pragma unroll
            for (int ct = 0; ct < 8; ct++) {
                int col = ct * 16 + l15;
                X[(size_t)row * HIDDEN + col] = (vv[ct][r] - mean) * inv * gcol[ct] + bcol2[ct];
            }
        }
    }
}

extern "C" void kernel_launch(void* const* d_in, const int* in_sizes, int n_in,
                              void* d_out, int out_size, void* d_ws, size_t ws_size,
                              hipStream_t stream) {
    const float* llm   = (const float*)d_in[0];
    const int*   sid   = (const int*)d_in[1];
    const int*   eidx  = (const int*)d_in[2];
    const float* projW = (const float*)d_in[3];
    const float* projb = (const float*)d_in[4];
    const float* emb   = (const float*)d_in[5];
    const float* gcnW  = (const float*)d_in[6];
    const float* gcnb  = (const float*)d_in[7];
    const float* lng   = (const float*)d_in[8];
    const float* lnb   = (const float*)d_in[9];

    float* X = (float*)d_out;                                   // [N,128] fp32
    unsigned short* Xs = (unsigned short*)d_ws;                 // [N,128] bf16
    unsigned short* Gb = Xs + (size_t)N_NODES * HIDDEN;         // [N,128] bf16
    unsigned short* Wt = Gb;                                    // [112,640] bf16 (overlaps Gb: dead before gather)
    unsigned short* Wt2 = Gb + (size_t)N_NODES * HIDDEN;        // [2,128,128] bf16
    float* dis = (float*)(Wt2 + 2 * HIDDEN * HIDDEN);           // [N]
    int* cnt  = (int*)(dis + N_NODES);                          // [N] (reused as pos)
    int* offs = cnt + N_NODES;                                  // [N+1]
    int* bsum = offs + N_NODES + 1;                             // [128]
    int* bpre = bsum + 128;                                     // [128]
    int* srcs = bpre + 128;                                     // [E]

    hipMemsetAsync(cnt, 0, N_NODES * sizeof(int), stream);
    deg_count<<<(E_EDGES + 255) / 256, 256, 0, stream>>>(eidx, cnt);
    make_dis<<<(N_NODES + 255) / 256, 256, 0, stream>>>(cnt, dis);
    scan_blocksum<<<NB_SCAN, 256, 0, stream>>>(cnt, bsum);
    scan_bsum<<<1, 128, 0, stream>>>(bsum, bpre);
    scan_offs<<<NB_SCAN, 256, 0, stream>>>(cnt, bpre, offs);
    hipMemsetAsync(cnt, 0, N_NODES * sizeof(int), stream);      // cnt -> pos
    fill_srcs<<<(E_EDGES + 255) / 256, 256, 0, stream>>>(eidx, offs, cnt, srcs);

    wt_convert<<<(POUT * LLM_DIM + 255) / 256, 256, 0, stream>>>(projW, Wt);
    w2_convert<<<(2 * HIDDEN * HIDDEN + 255) / 256, 256, 0, stream>>>(gcnW, Wt2);

    const int nwaves = (N_NODES + 15) / 16;          // 3125
    const int nblk = (nwaves + 3) / 4;               // 782
    proj_mfma<<<nblk, 256, 0, stream>>>(llm, Wt, projb, emb, sid, dis, X, Xs);

    gather<<<(N_NODES + 3) / 4, 256, 0, stream>>>(Xs, offs, srcs, dis, Gb);
    gemm_fin<0><<<nblk, 256, 0, stream>>>(Gb, Wt2, gcnb, dis, lng, lnb, X, Xs);
    gather<<<(N_NODES + 3) / 4, 256, 0, stream>>>(Xs, offs, srcs, dis, Gb);
    gemm_fin<1><<<nblk, 256, 0, stream>>>(Gb, Wt2 + HIDDEN * HIDDEN, gcnb + HIDDEN, dis, lng, lnb, X, Xs);
}